// Round 1
// baseline (174.513 us; speedup 1.0000x reference)
//
#include <hip/hip_runtime.h>
#include <math.h>

#define NN 5000      // nodes
#define GG 16        // graphs (B*D)
#define VV 256       // vocab
#define FF 64        // in channels
#define HH 4         // heads
#define CC 32        // channels/head
#define HC 128       // H*C
#define EE 80000     // edges before self loops
#define NEG 0.2f
#define WPB 4        // waves per block in main kernel

// ---------------------------------------------------------------------------
// Kernel 1: T = emb @ W  [V][HC], plus a_s_t[V][H], a_d_t[V][H]
// ---------------------------------------------------------------------------
__global__ void k_tables(const float* __restrict__ emb, const float* __restrict__ W,
                         const float* __restrict__ att_src, const float* __restrict__ att_dst,
                         float* __restrict__ T, float* __restrict__ as_t, float* __restrict__ ad_t) {
  __shared__ float se[FF];
  __shared__ float sT[HC];
  const int v = blockIdx.x;
  const int k = threadIdx.x;          // 0..127
  if (k < FF) se[k] = emb[v * FF + k];
  __syncthreads();
  float acc = 0.f;
#pragma unroll
  for (int f = 0; f < FF; ++f) acc += se[f] * W[f * HC + k];
  T[v * HC + k] = acc;
  sT[k] = acc;
  __syncthreads();
  if (k < 2 * HH) {
    const int h = k >> 1;
    const float* att = (k & 1) ? att_dst : att_src;
    float s = 0.f;
#pragma unroll
    for (int c = 0; c < CC; ++c) s += sT[h * CC + c] * att[h * CC + c];
    if (k & 1) ad_t[v * HH + h] = s;
    else       as_t[v * HH + h] = s;
  }
}

// ---------------------------------------------------------------------------
// CSR build (adjacency is shared by all graphs). Self loop goes in slot 0.
// ---------------------------------------------------------------------------
__global__ void k_init_cnt(int* __restrict__ cnt) {
  int n = blockIdx.x * blockDim.x + threadIdx.x;
  if (n < NN) cnt[n] = 1;   // self loop
}

__global__ void k_count(const int* __restrict__ dst, int* __restrict__ cnt) {
  int e = blockIdx.x * blockDim.x + threadIdx.x;
  if (e < EE) atomicAdd(&cnt[dst[e]], 1);
}

// single block, 256 threads, chunk of 20 per thread (256*20 >= 5000)
__global__ void k_scan(const int* __restrict__ cnt, int* __restrict__ off,
                       int* __restrict__ cursor, int* __restrict__ csr) {
  __shared__ int part[256];
  const int t = threadIdx.x;
  const int CH = (NN + 255) / 256;    // 20
  const int i0 = t * CH;
  int lc[CH];
  int lsum = 0;
#pragma unroll
  for (int j = 0; j < CH; ++j) {
    int idx = i0 + j;
    int c = (idx < NN) ? cnt[idx] : 0;
    lc[j] = c;
    lsum += c;
  }
  part[t] = lsum;
  __syncthreads();
  for (int d = 1; d < 256; d <<= 1) {
    int val = (t >= d) ? part[t - d] : 0;
    __syncthreads();
    part[t] += val;
    __syncthreads();
  }
  int run = (t > 0) ? part[t - 1] : 0;  // exclusive prefix
#pragma unroll
  for (int j = 0; j < CH; ++j) {
    int idx = i0 + j;
    if (idx < NN) {
      off[idx] = run;
      cursor[idx] = run + 1;   // slot `run` reserved for self loop
      csr[run] = idx;          // self loop entry
      run += lc[j];
    }
  }
  if (t == 255) off[NN] = part[255];
}

__global__ void k_scatter(const int* __restrict__ src, const int* __restrict__ dst,
                          int* __restrict__ cursor, int* __restrict__ csr) {
  int e = blockIdx.x * blockDim.x + threadIdx.x;
  if (e < EE) {
    int d = dst[e];
    int pos = atomicAdd(&cursor[d], 1);
    csr[pos] = src[e];
  }
}

// ---------------------------------------------------------------------------
// Main kernel: one wave per (g, n). Chunked online softmax over in-edges,
// lane owns 2 of 128 output channels for the PV-style accumulation.
// ---------------------------------------------------------------------------
__global__ __launch_bounds__(256)
void k_gat(const int* __restrict__ x, const int* __restrict__ off,
           const int* __restrict__ csr, const float* __restrict__ T,
           const float* __restrict__ as_t, const float* __restrict__ ad_t,
           const float* __restrict__ bias, float* __restrict__ out) {
  __shared__ float4 s_as4[VV];                // 4 KB: a_s table
  __shared__ int    s_xv[WPB][64];            // 1 KB
  __shared__ float4 s_p4[WPB][64];            // 4 KB: per-edge exp() per head
  const int tid = threadIdx.x;
  for (int i = tid; i < VV; i += 256) s_as4[i] = ((const float4*)as_t)[i];
  __syncthreads();

  const int wave = tid >> 6;
  const int lane = tid & 63;
  const int id = blockIdx.x * WPB + wave;     // 0 .. GG*NN-1 (grid exact)
  const int g = id / NN;
  const int n = id - g * NN;

  const int base = off[n];
  const int deg  = off[n + 1] - base;
  const int xd   = x[g * NN + n];
  const float4 adv = ((const float4*)ad_t)[xd];

  const int k = lane * 2;                     // output channels k, k+1
  const int h = lane >> 4;                    // head of those channels

  float m0 = -__builtin_inff(), m1 = m0, m2 = m0, m3 = m0;
  float s0 = 0.f, s1 = 0.f, s2 = 0.f, s3 = 0.f;
  float accx = 0.f, accy = 0.f;

  for (int c0 = 0; c0 < deg; c0 += 64) {
    const int len = min(64, deg - c0);
    const bool valid = lane < len;
    int srcn = 0, xv = 0;
    if (valid) {
      srcn = csr[base + c0 + lane];
      xv   = x[g * NN + srcn];
    }
    const float4 as4 = s_as4[xv];
    float e0 = adv.x + as4.x; e0 = e0 > 0.f ? e0 : NEG * e0;
    float e1 = adv.y + as4.y; e1 = e1 > 0.f ? e1 : NEG * e1;
    float e2 = adv.z + as4.z; e2 = e2 > 0.f ? e2 : NEG * e2;
    float e3 = adv.w + as4.w; e3 = e3 > 0.f ? e3 : NEG * e3;
    if (!valid) { e0 = e1 = e2 = e3 = -__builtin_inff(); }

    // chunk max (butterfly over 64 lanes)
    float mc0 = e0, mc1 = e1, mc2 = e2, mc3 = e3;
#pragma unroll
    for (int d = 32; d; d >>= 1) {
      mc0 = fmaxf(mc0, __shfl_xor(mc0, d));
      mc1 = fmaxf(mc1, __shfl_xor(mc1, d));
      mc2 = fmaxf(mc2, __shfl_xor(mc2, d));
      mc3 = fmaxf(mc3, __shfl_xor(mc3, d));
    }
    const float nm0 = fmaxf(m0, mc0), nm1 = fmaxf(m1, mc1);
    const float nm2 = fmaxf(m2, mc2), nm3 = fmaxf(m3, mc3);

    float p0 = valid ? __expf(e0 - nm0) : 0.f;
    float p1 = valid ? __expf(e1 - nm1) : 0.f;
    float p2 = valid ? __expf(e2 - nm2) : 0.f;
    float p3 = valid ? __expf(e3 - nm3) : 0.f;

    float cs0 = p0, cs1 = p1, cs2 = p2, cs3 = p3;
#pragma unroll
    for (int d = 32; d; d >>= 1) {
      cs0 += __shfl_xor(cs0, d);
      cs1 += __shfl_xor(cs1, d);
      cs2 += __shfl_xor(cs2, d);
      cs3 += __shfl_xor(cs3, d);
    }
    // rescale running state (first chunk: expf(-inf)=0, s starts at 0)
    const float sc0 = __expf(m0 - nm0), sc1 = __expf(m1 - nm1);
    const float sc2 = __expf(m2 - nm2), sc3 = __expf(m3 - nm3);
    s0 = s0 * sc0 + cs0; s1 = s1 * sc1 + cs1;
    s2 = s2 * sc2 + cs2; s3 = s3 * sc3 + cs3;
    m0 = nm0; m1 = nm1; m2 = nm2; m3 = nm3;

    const float sch = (h < 2) ? (h == 0 ? sc0 : sc1) : (h == 2 ? sc2 : sc3);
    accx *= sch; accy *= sch;

    // publish chunk edges to the wave
    s_xv[wave][lane] = xv;
    s_p4[wave][lane] = make_float4(p0, p1, p2, p3);
    __threadfence_block();   // drain LDS writes (same-wave cross-lane RAW)

    const float* pbase = (const float*)&s_p4[wave][0];
    for (int j = 0; j < len; ++j) {
      const int   xv2 = s_xv[wave][j];
      const float pv  = pbase[j * 4 + h];          // broadcast within head group
      const float2 t2 = *(const float2*)&T[xv2 * HC + k];
      accx += pv * t2.x;
      accy += pv * t2.y;
    }
    __threadfence_block();   // WAR guard before next chunk overwrites buffers
  }

  const float sh = (h < 2) ? (h == 0 ? s0 : s1) : (h == 2 ? s2 : s3);
  const float r = 1.f / sh;
  const float2 b2 = *(const float2*)&bias[k];
  float2 o;
  o.x = accx * r + b2.x;
  o.y = accy * r + b2.y;
  *(float2*)&out[(size_t)id * HC + k] = o;
}

// ---------------------------------------------------------------------------
extern "C" void kernel_launch(void* const* d_in, const int* in_sizes, int n_in,
                              void* d_out, int out_size, void* d_ws, size_t ws_size,
                              hipStream_t stream) {
  const int*   x       = (const int*)d_in[0];      // [G,N]
  const int*   adj     = (const int*)d_in[1];      // [2,E]
  const float* emb     = (const float*)d_in[2];    // [V,F]
  const float* W       = (const float*)d_in[3];    // [F,HC]
  const float* att_src = (const float*)d_in[4];    // [H,C]
  const float* att_dst = (const float*)d_in[5];    // [H,C]
  const float* bias    = (const float*)d_in[6];    // [HC]
  float*       out     = (float*)d_out;

  const int* adj_src = adj;
  const int* adj_dst = adj + EE;

  // workspace carve-up (16B aligned regions)
  char* w = (char*)d_ws;
  float* T    = (float*)w; w += (size_t)VV * HC * 4;         // 128 KB
  float* as_t = (float*)w; w += (size_t)VV * HH * 4;         // 4 KB
  float* ad_t = (float*)w; w += (size_t)VV * HH * 4;         // 4 KB
  int* cnt    = (int*)w;   w += ((NN + 3) & ~3) * 4;
  int* off    = (int*)w;   w += ((NN + 1 + 3) & ~3) * 4;
  int* cursor = (int*)w;   w += ((NN + 3) & ~3) * 4;
  int* csr    = (int*)w;   w += ((EE + NN + 3) & ~3) * 4;    // 85000 entries

  k_tables<<<VV, HC, 0, stream>>>(emb, W, att_src, att_dst, T, as_t, ad_t);
  k_init_cnt<<<(NN + 255) / 256, 256, 0, stream>>>(cnt);
  k_count<<<(EE + 255) / 256, 256, 0, stream>>>(adj_dst, cnt);
  k_scan<<<1, 256, 0, stream>>>(cnt, off, cursor, csr);
  k_scatter<<<(EE + 255) / 256, 256, 0, stream>>>(adj_src, adj_dst, cursor, csr);
  k_gat<<<(GG * NN) / WPB, 256, 0, stream>>>(x, off, csr, T, as_t, ad_t, bias, out);
}

// Round 2
// 139.197 us; speedup vs baseline: 1.2537x; 1.2537x over previous
//
#include <hip/hip_runtime.h>
#include <math.h>

#define NN 5000      // nodes
#define GG 16        // graphs (B*D)
#define VV 256       // vocab
#define FF 64        // in channels
#define HH 4         // heads
#define CC 32        // channels/head
#define HC 128       // H*C
#define EE 80000     // edges before self loops
#define NEG 0.2f
#define WPB 4        // waves per block in main kernel
#define SLOT 48      // edge chunk per node (deg>48 handled by outer loop; never hit for Poisson(17))
#define SPAD 50      // padded slot stride: 50*4 dwords %32 = 8 -> sub-groups on distinct banks

// ---------------------------------------------------------------------------
// Kernel A: T = emb @ W  [V][HC] + a_s_t[V][H], a_d_t[V][H]; tail blocks init cnt=1
// ---------------------------------------------------------------------------
__global__ void k_tables(const float* __restrict__ emb, const float* __restrict__ W,
                         const float* __restrict__ att_src, const float* __restrict__ att_dst,
                         float* __restrict__ T, float* __restrict__ as_t, float* __restrict__ ad_t,
                         int* __restrict__ cnt) {
  if (blockIdx.x >= VV) {
    int n = (blockIdx.x - VV) * 128 + threadIdx.x;
    if (n < NN) cnt[n] = 1;   // self loop pre-count
    return;
  }
  __shared__ float se[FF];
  __shared__ float sT[HC];
  const int v = blockIdx.x;
  const int k = threadIdx.x;          // 0..127
  if (k < FF) se[k] = emb[v * FF + k];
  __syncthreads();
  float acc = 0.f;
#pragma unroll
  for (int f = 0; f < FF; ++f) acc += se[f] * W[f * HC + k];
  T[v * HC + k] = acc;
  sT[k] = acc;
  __syncthreads();
  if (k < 2 * HH) {
    const int h = k >> 1;
    const float* att = (k & 1) ? att_dst : att_src;
    float s = 0.f;
#pragma unroll
    for (int c = 0; c < CC; ++c) s += sT[h * CC + c] * att[h * CC + c];
    if (k & 1) ad_t[v * HH + h] = s;
    else       as_t[v * HH + h] = s;
  }
}

// ---------------------------------------------------------------------------
// CSR build (adjacency shared by all graphs). Self loop in slot 0.
// ---------------------------------------------------------------------------
__global__ void k_count(const int* __restrict__ dst, int* __restrict__ cnt) {
  int e = blockIdx.x * blockDim.x + threadIdx.x;
  if (e < EE) atomicAdd(&cnt[dst[e]], 1);
}

// single block, 256 threads
__global__ void k_scan(const int* __restrict__ cnt, int* __restrict__ off,
                       int* __restrict__ cursor, int* __restrict__ csr) {
  __shared__ int part[256];
  const int t = threadIdx.x;
  const int CH = (NN + 255) / 256;    // 20
  const int i0 = t * CH;
  int lc[CH];
  int lsum = 0;
#pragma unroll
  for (int j = 0; j < CH; ++j) {
    int idx = i0 + j;
    int c = (idx < NN) ? cnt[idx] : 0;
    lc[j] = c;
    lsum += c;
  }
  part[t] = lsum;
  __syncthreads();
  for (int d = 1; d < 256; d <<= 1) {
    int val = (t >= d) ? part[t - d] : 0;
    __syncthreads();
    part[t] += val;
    __syncthreads();
  }
  int run = (t > 0) ? part[t - 1] : 0;  // exclusive prefix
#pragma unroll
  for (int j = 0; j < CH; ++j) {
    int idx = i0 + j;
    if (idx < NN) {
      off[idx] = run;
      cursor[idx] = run + 1;   // slot `run` reserved for self loop
      csr[run] = idx;          // self loop entry
      run += lc[j];
    }
  }
  if (t == 255) off[NN] = part[255];
}

// Kernel D: scatter (blocks 0..NSCAT-1) + P table (blocks NSCAT..NSCAT+255)
// P[d*VV+v] (float4 over heads) = exp(leaky_relu(as[v] + ad[d]))
#define NSCAT ((EE + 255) / 256)
__global__ void k_scatter_p(const int* __restrict__ src, const int* __restrict__ dst,
                            int* __restrict__ cursor, int* __restrict__ csr,
                            const float* __restrict__ as_t, const float* __restrict__ ad_t,
                            float* __restrict__ P) {
  if (blockIdx.x < NSCAT) {
    int e = blockIdx.x * 256 + threadIdx.x;
    if (e < EE) {
      int d = dst[e];
      int pos = atomicAdd(&cursor[d], 1);
      csr[pos] = src[e];
    }
    return;
  }
  const int d = blockIdx.x - NSCAT;   // 0..255
  const int v = threadIdx.x;          // 0..255
  const float4 a = ((const float4*)as_t)[v];
  const float4 b = ((const float4*)ad_t)[d];
  float e0 = a.x + b.x; e0 = e0 > 0.f ? e0 : NEG * e0;
  float e1 = a.y + b.y; e1 = e1 > 0.f ? e1 : NEG * e1;
  float e2 = a.z + b.z; e2 = e2 > 0.f ? e2 : NEG * e2;
  float e3 = a.w + b.w; e3 = e3 > 0.f ? e3 : NEG * e3;
  float4 p;
  p.x = __expf(e0); p.y = __expf(e1); p.z = __expf(e2); p.w = __expf(e3);
  ((float4*)P)[d * VV + v] = p;
}

// ---------------------------------------------------------------------------
// Main kernel: one wave handles 4 consecutive node-instances (16 lanes each).
// Per node: gather edges (p4 = P[xd][xv] lookup, no exp/max in hot loop),
// then each of its 16 lanes accumulates 8 output channels over the edges.
// ---------------------------------------------------------------------------
__global__ __launch_bounds__(256)
void k_gat(const int* __restrict__ x, const int* __restrict__ off,
           const int* __restrict__ csr, const float* __restrict__ T,
           const float* __restrict__ P, const float* __restrict__ bias,
           float* __restrict__ out) {
  __shared__ float4 s_p4[WPB][4][SPAD];   // 4*4*50*16 = 12800 B
  __shared__ int    s_ofs[WPB][4][SPAD];  // 4*4*50*4  =  3200 B

  const int tid  = threadIdx.x;
  const int wave = tid >> 6;
  const int lane = tid & 63;
  const int sub  = lane >> 4;             // which of 4 nodes
  const int sl   = lane & 15;             // sub-lane within node group
  const int head = sl >> 2;               // my 8 channels live in this head

  const int w    = blockIdx.x * WPB + wave;   // 0..GG*NN/4-1 (grid exact)
  const int inst = w * 4 + sub;               // = g*NN + n  (NN%4==0 -> same g per wave)
  const int g    = inst / NN;
  const int n    = inst - g * NN;

  const int base = off[n];
  const int deg  = off[n + 1] - base;
  const int xd   = x[inst];
  const float4* __restrict__ Pd = ((const float4*)P) + xd * VV;
  const int* __restrict__ xg = x + g * NN;

  const int my_ch = sl * 8;
  const float4 b0 = ((const float4*)bias)[sl * 2];
  const float4 b1 = ((const float4*)bias)[sl * 2 + 1];

  float4 dsum = make_float4(0.f, 0.f, 0.f, 0.f);
  float4 a0 = make_float4(0.f, 0.f, 0.f, 0.f);
  float4 a1 = make_float4(0.f, 0.f, 0.f, 0.f);

  for (int c0 = 0; c0 < deg; c0 += SLOT) {
    const int len = min(SLOT, deg - c0);
    // gather phase: 16 sub-lanes stride over this node's edges
    for (int r = sl; r < len; r += 16) {
      const int srcn = csr[base + c0 + r];
      const int xv   = xg[srcn];
      const float4 p4 = Pd[xv];
      dsum.x += p4.x; dsum.y += p4.y; dsum.z += p4.z; dsum.w += p4.w;
      s_p4[wave][sub][r]  = p4;
      s_ofs[wave][sub][r] = xv << 7;   // xv*HC element offset into T
    }
    __threadfence_block();   // drain LDS writes before cross-lane reads
    // channel phase: every lane accumulates its 8 channels over len edges
#pragma unroll 2
    for (int j = 0; j < len; ++j) {
      const int   ofs = s_ofs[wave][sub][j];
      const float p   = ((const float*)&s_p4[wave][sub][j])[head];
      const float4 t0 = *(const float4*)&T[ofs + my_ch];
      const float4 t1 = *(const float4*)&T[ofs + my_ch + 4];
      a0.x += p * t0.x; a0.y += p * t0.y; a0.z += p * t0.z; a0.w += p * t0.w;
      a1.x += p * t1.x; a1.y += p * t1.y; a1.z += p * t1.z; a1.w += p * t1.w;
    }
    __threadfence_block();   // WAR guard before next chunk overwrites buffers
  }

  // denominator: butterfly over the 16-lane group (xor 1,2,4,8 stays in group)
#pragma unroll
  for (int d = 1; d < 16; d <<= 1) {
    dsum.x += __shfl_xor(dsum.x, d);
    dsum.y += __shfl_xor(dsum.y, d);
    dsum.z += __shfl_xor(dsum.z, d);
    dsum.w += __shfl_xor(dsum.w, d);
  }
  const float den = (head == 0) ? dsum.x : (head == 1) ? dsum.y
                   : (head == 2) ? dsum.z : dsum.w;
  const float r = 1.f / den;

  float4 o0, o1;
  o0.x = a0.x * r + b0.x; o0.y = a0.y * r + b0.y;
  o0.z = a0.z * r + b0.z; o0.w = a0.w * r + b0.w;
  o1.x = a1.x * r + b1.x; o1.y = a1.y * r + b1.y;
  o1.z = a1.z * r + b1.z; o1.w = a1.w * r + b1.w;
  float* op = out + (size_t)inst * HC + my_ch;
  *(float4*)op = o0;
  *(float4*)(op + 4) = o1;
}

// ---------------------------------------------------------------------------
extern "C" void kernel_launch(void* const* d_in, const int* in_sizes, int n_in,
                              void* d_out, int out_size, void* d_ws, size_t ws_size,
                              hipStream_t stream) {
  const int*   x       = (const int*)d_in[0];      // [G,N]
  const int*   adj     = (const int*)d_in[1];      // [2,E]
  const float* emb     = (const float*)d_in[2];    // [V,F]
  const float* W       = (const float*)d_in[3];    // [F,HC]
  const float* att_src = (const float*)d_in[4];    // [H,C]
  const float* att_dst = (const float*)d_in[5];    // [H,C]
  const float* bias    = (const float*)d_in[6];    // [HC]
  float*       out     = (float*)d_out;

  const int* adj_src = adj;
  const int* adj_dst = adj + EE;

  // workspace carve-up (all region sizes are multiples of 16 B)
  char* wp = (char*)d_ws;
  float* T    = (float*)wp; wp += (size_t)VV * HC * 4;       // 128 KB
  float* as_t = (float*)wp; wp += (size_t)VV * HH * 4;       // 4 KB
  float* ad_t = (float*)wp; wp += (size_t)VV * HH * 4;       // 4 KB
  int* cnt    = (int*)wp;   wp += (size_t)NN * 4;            // 20000 B
  int* off    = (int*)wp;   wp += (size_t)(NN + 4) * 4;      // 20016 B
  int* cursor = (int*)wp;   wp += (size_t)NN * 4;            // 20000 B
  int* csr    = (int*)wp;   wp += (size_t)(EE + NN) * 4;     // 340000 B
  float* P    = (float*)wp; wp += (size_t)VV * VV * HH * 4;  // 1 MB

  const int initblk = (NN + 127) / 128;                      // 40
  k_tables<<<VV + initblk, 128, 0, stream>>>(emb, W, att_src, att_dst, T, as_t, ad_t, cnt);
  k_count<<<(EE + 255) / 256, 256, 0, stream>>>(adj_dst, cnt);
  k_scan<<<1, 256, 0, stream>>>(cnt, off, cursor, csr);
  k_scatter_p<<<NSCAT + VV, 256, 0, stream>>>(adj_src, adj_dst, cursor, csr, as_t, ad_t, P);
  k_gat<<<(GG * NN / 4) / WPB, 256, 0, stream>>>(x, off, csr, T, P, bias, out);
}